// Round 3
// baseline (332.213 us; speedup 1.0000x reference)
//
#include <hip/hip_runtime.h>

#define NPOS 16384
#define NEG  (-1e30f)

// workspace offsets (in floats)
#define OFF_WQX_F 0
#define OFF_WQX_B 4096
#define OFF_WQH_F 8192
#define OFF_WQH_B 9216
#define OFF_BQ_F  10240
#define OFF_BQ_B  10304
#define OFF_YP2   10368
#define OFF_ZB    10608
#define OFF_XG_F  16384
#define OFF_XG_B  (OFF_XG_F + 16384*64)
// h states stored as bf16 (ushort); float-offset base, cast to ushort*
#define OFF_FWDH  (OFF_XG_B + 16384*64)
#define OFF_BWDH  (OFF_FWDH + 15*16384*16/2)
#define OFF_A     (OFF_BWDH + 15*16384*16/2)
#define OFF_T0    (OFF_A + 16384*16)
#define OFF_T1    (OFF_T0 + 256*225)
#define OFF_GSC   (OFF_T1 + 128*225)

__device__ __forceinline__ float sigf(float x) {
    return __builtin_amdgcn_rcpf(1.0f + __expf(-x));
}
__device__ __forceinline__ float tanhf_(float x) {
    return 1.0f - 2.0f * __builtin_amdgcn_rcpf(1.0f + __expf(2.0f * x));
}
__device__ __forceinline__ float bf2f(unsigned short u) {
    unsigned int v = ((unsigned int)u) << 16;
    return __builtin_bit_cast(float, v);
}
__device__ __forceinline__ unsigned short f2bf(float f) {
    unsigned int b = __builtin_bit_cast(unsigned int, f);
    return (unsigned short)((b + 0x8000u) >> 16);
}
// tree logsumexp over 15 values (shallow dependent chain)
__device__ __forceinline__ float lse15(const float* tv) {
    float a0 = fmaxf(tv[0], tv[1]),  a1 = fmaxf(tv[2], tv[3]);
    float a2 = fmaxf(tv[4], tv[5]),  a3 = fmaxf(tv[6], tv[7]);
    float a4 = fmaxf(tv[8], tv[9]),  a5 = fmaxf(tv[10], tv[11]);
    float a6 = fmaxf(tv[12], tv[13]);
    float b0 = fmaxf(a0, a1), b1 = fmaxf(a2, a3), b2 = fmaxf(a4, a5), b3 = fmaxf(a6, tv[14]);
    float mx = fmaxf(fmaxf(b0, b1), fmaxf(b2, b3));
    float e[15];
    #pragma unroll
    for (int i = 0; i < 15; i++) e[i] = __expf(tv[i] - mx);
    float s0 = e[0]+e[1], s1 = e[2]+e[3], s2 = e[4]+e[5], s3 = e[6]+e[7];
    float s4 = e[8]+e[9], s5 = e[10]+e[11], s6 = e[12]+e[13];
    float t0 = s0+s1, t1 = s2+s3, t2 = s4+s5, t3 = s6+e[14];
    return mx + __logf((t0+t1) + (t2+t3));
}

// ---------------------------------------------------------------- prep
// Packed gate order widx = w*8+jj maps to logical gate j = (jj>>1)*16 + 2w + (jj&1).
__global__ void k_prep(const float* __restrict__ fWih, const float* __restrict__ fWhh,
                       const float* __restrict__ fbih, const float* __restrict__ fbhh,
                       const float* __restrict__ bWih, const float* __restrict__ bWhh,
                       const float* __restrict__ bbih, const float* __restrict__ bbhh,
                       const float* __restrict__ Yenc, const float* __restrict__ Zenc,
                       const float* __restrict__ VW,   const float* __restrict__ Vb,
                       float* __restrict__ wp)
{
    int t = threadIdx.x;
    for (int e = t; e < 8192; e += 256) {           // Wih pack: [k][widx]
        int dir = e >> 12, rem = e & 4095;
        int k = rem >> 6, widx = rem & 63;
        int w = widx >> 3, jj = widx & 7;
        int j = (jj >> 1) * 16 + 2 * w + (jj & 1);
        const float* Wih = dir ? bWih : fWih;
        wp[(dir ? OFF_WQX_B : OFF_WQX_F) + rem] = Wih[j * 64 + k];
    }
    for (int e = t; e < 2048; e += 256) {           // Whh pack: [m][widx]
        int dir = e >> 10, rem = e & 1023;
        int m = rem >> 6, widx = rem & 63;
        int w = widx >> 3, jj = widx & 7;
        int j = (jj >> 1) * 16 + 2 * w + (jj & 1);
        const float* Whh = dir ? bWhh : fWhh;
        wp[(dir ? OFF_WQH_B : OFF_WQH_F) + rem] = Whh[j * 16 + m];
    }
    for (int e = t; e < 128; e += 256) {
        int dir = e >> 6, widx = e & 63;
        int w = widx >> 3, jj = widx & 7;
        int j = (jj >> 1) * 16 + 2 * w + (jj & 1);
        const float* bi = dir ? bbih : fbih;
        const float* bh = dir ? bbhh : fbhh;
        wp[(dir ? OFF_BQ_B : OFF_BQ_F) + widx] = bi[j] + bh[j];
    }
    for (int e = t; e < 240; e += 256) {
        int y = e >> 4, h = e & 15;
        float acc = 0.f;                            // yp2 = 2 * (Y_enc @ V2^T)
        for (int tt = 0; tt < 32; tt++) acc += Yenc[y*32+tt] * VW[h*68 + 32 + tt];
        wp[OFF_YP2 + e] = 2.0f * acc;
        float z = Vb[h];                            // zb = Z_enc @ V3^T + V_b
        for (int u = 0; u < 4; u++) z += Zenc[y*4+u] * VW[h*68 + 64 + u];
        wp[OFF_ZB + e] = z;
    }
}

// ---------------------------------------------------------------- xg = x @ Wih^T + b  (once per position)
// grid (256,2), 512 thr = 8 waves; wave wv owns 8 packed gates; lane = position.
__global__ __launch_bounds__(512) void k_xg(const float* __restrict__ data,
                                            const float* __restrict__ wp,
                                            float* __restrict__ ws)
{
    const int lane = threadIdx.x & 63;
    const int wv   = __builtin_amdgcn_readfirstlane(threadIdx.x >> 6);
    const int dir  = blockIdx.y;
    const int pos  = (blockIdx.x << 6) + lane;
    const float* WQX = wp + (dir ? OFF_WQX_B : OFF_WQX_F);
    const float* bQ  = wp + (dir ? OFF_BQ_B  : OFF_BQ_F);
    float* xg = ws + (dir ? OFF_XG_B : OFF_XG_F);

    float xv[64];
    const float4* xrow = (const float4*)(data + (size_t)pos * 64);
    #pragma unroll
    for (int q = 0; q < 16; q++) {
        float4 v = xrow[q];
        xv[4*q] = v.x; xv[4*q+1] = v.y; xv[4*q+2] = v.z; xv[4*q+3] = v.w;
    }
    float acc[8];
    #pragma unroll
    for (int jj = 0; jj < 8; jj++) acc[jj] = bQ[wv*8 + jj];
    #pragma unroll 8
    for (int k = 0; k < 64; k++) {
        float xk = xv[k];
        #pragma unroll
        for (int jj = 0; jj < 8; jj++)
            acc[jj] = fmaf(WQX[k*64 + wv*8 + jj], xk, acc[jj]);
    }
    float4* outp = (float4*)(xg + (size_t)pos*64 + wv*8);
    outp[0] = make_float4(acc[0], acc[1], acc[2], acc[3]);
    outp[1] = make_float4(acc[4], acc[5], acc[6], acc[7]);
}

// ---------------------------------------------------------------- LSTM (recurrent part only)
// grid (256,2): blockIdx.y = dir. 512 thr = 8 waves; wave wv owns hidden units
// {2wv, 2wv+1} (all 4 gates). lane = position. xg staged transposed [gate][row]
// stride 79 (conflict-free both ways). One barrier/step, h dbuf, out bf16.
__global__ __launch_bounds__(512) void k_lstm(const float* __restrict__ wp,
    const float* __restrict__ h0f, const float* __restrict__ c0f,
    const float* __restrict__ h0b, const float* __restrict__ c0b,
    float* __restrict__ ws)
{
    __shared__ float xgT[64*79];      // [gate j][row r], rows 0..77
    __shared__ float hsh[2][16*64];   // double-buffered h
    const int tid  = threadIdx.x;
    const int lane = tid & 63;
    const int wv   = __builtin_amdgcn_readfirstlane(tid >> 6);
    const int dir  = blockIdx.y;
    const int ms   = wv << 1;
    const int P0   = blockIdx.x << 6;

    const float* xg = ws + (dir ? OFF_XG_B : OFF_XG_F);
    for (int idx = tid; idx < 78*64; idx += 512) {
        int r = idx >> 6, j = idx & 63;
        int q = P0 + r - (dir ? 14 : 0);
        q = q < 0 ? 0 : (q > NPOS-1 ? NPOS-1 : q);
        xgT[j*79 + r] = xg[(size_t)q*64 + j];
    }
    {
        const float* h0 = dir ? h0b : h0f;
        for (int idx = tid; idx < 1024; idx += 512)
            hsh[0][idx] = h0[idx >> 6];
    }
    const float* WQH = wp + (dir ? OFF_WQH_B : OFF_WQH_F);
    const float* c0 = dir ? c0b : c0f;
    unsigned int* outH = (unsigned int*)(ws + (dir ? OFF_BWDH : OFF_FWDH));
    float c0v = c0[ms], c1v = c0[ms + 1];
    __syncthreads();

    int buf = 0;
    for (int d = 0; d < 15; d++) {
        const int row = dir ? (lane + 14 - d) : (lane + d);
        float part[8];
        #pragma unroll
        for (int jj = 0; jj < 8; jj++) part[jj] = xgT[(wv*8 + jj)*79 + row];
        #pragma unroll
        for (int m = 0; m < 16; m++) {
            float hm = hsh[buf][m*64 + lane];
            #pragma unroll
            for (int jj = 0; jj < 8; jj++)
                part[jj] = fmaf(WQH[m*64 + wv*8 + jj], hm, part[jj]);
        }
        float cn0 = sigf(part[2])*c0v + sigf(part[0])*tanhf_(part[4]);
        float cn1 = sigf(part[3])*c1v + sigf(part[1])*tanhf_(part[5]);
        c0v = cn0; c1v = cn1;
        float h0v = sigf(part[6])*tanhf_(cn0);
        float h1v = sigf(part[7])*tanhf_(cn1);
        hsh[buf^1][ms*64 + lane]     = h0v;
        hsh[buf^1][(ms+1)*64 + lane] = h1v;
        unsigned int pk = (unsigned int)f2bf(h0v) | ((unsigned int)f2bf(h1v) << 16);
        outH[((size_t)d*NPOS + P0 + lane)*8 + wv] = pk;
        __syncthreads();
        buf ^= 1;
    }
}

// ---------------------------------------------------------------- scores + A
// thread = (p, d); sum_h w*tanh via identity: sum(w) - 2*sum(w/(1+e^{2x}))
__global__ __launch_bounds__(256) void k_scores(float* __restrict__ ws,
    const float* __restrict__ VW, const float* __restrict__ WW,
    const float* __restrict__ Wb)
{
    const int g = blockIdx.x * 256 + threadIdx.x;
    const int p = g & (NPOS - 1);
    const int d = __builtin_amdgcn_readfirstlane(g >> 14);
    float* A16 = ws + OFF_A;
    if (d == 0) A16[p*16 + 15] = NEG;   // pad column
    if (p < d) { A16[p*16 + d] = NEG; return; }

    const uint4* fptr = (const uint4*)((const unsigned short*)(ws + OFF_FWDH)
                        + ((size_t)d*NPOS + (p - d))*16);
    const uint4* bptr = (const uint4*)((const unsigned short*)(ws + OFF_BWDH)
                        + ((size_t)d*NPOS + p)*16);
    float fb0[16], fb1[16];
    #pragma unroll
    for (int q = 0; q < 2; q++) {
        uint4 v = fptr[q];
        unsigned int ww[4] = {v.x, v.y, v.z, v.w};
        #pragma unroll
        for (int t = 0; t < 4; t++) {
            fb0[q*8 + 2*t]     = bf2f((unsigned short)(ww[t] & 0xffff));
            fb0[q*8 + 2*t + 1] = bf2f((unsigned short)(ww[t] >> 16));
        }
        uint4 u = bptr[q];
        unsigned int uu[4] = {u.x, u.y, u.z, u.w};
        #pragma unroll
        for (int t = 0; t < 4; t++) {
            fb1[q*8 + 2*t]     = bf2f((unsigned short)(uu[t] & 0xffff));
            fb1[q*8 + 2*t + 1] = bf2f((unsigned short)(uu[t] >> 16));
        }
    }
    const float* zb  = ws + OFF_ZB + d*16;
    const float* yp2 = ws + OFF_YP2;
    float base2[16], w2[16], wsum = 0.f;
    #pragma unroll
    for (int h = 0; h < 16; h++) {
        float acc = zb[h];
        #pragma unroll
        for (int m = 0; m < 16; m++) acc = fmaf(VW[h*68 + m],      fb0[m], acc);
        #pragma unroll
        for (int m = 0; m < 16; m++) acc = fmaf(VW[h*68 + 16 + m], fb1[m], acc);
        base2[h] = acc + acc;
        float w = WW[h];
        w2[h] = -2.0f * w;
        wsum += w;
    }
    const float cst = Wb[0] + wsum;
    float sc[15];
    #pragma unroll
    for (int y = 0; y < 15; y++) {
        float a = 0.f;
        #pragma unroll
        for (int h = 0; h < 16; h++) {
            float t = __expf(base2[h] + yp2[y*16 + h]);
            a = fmaf(w2[h], __builtin_amdgcn_rcpf(1.0f + t), a);
        }
        sc[y] = cst + a;
    }
    A16[p*16 + d] = lse15(sc);
    if (p == d && p < 15) {
        float* gsc = ws + OFF_GSC;
        #pragma unroll
        for (int y = 0; y < 15; y++) gsc[p*15 + y] = sc[y];
    }
}

// ---------------------------------------------------------------- DP chunk transfer matrices
// 256 chunks of 64 steps; thread = basis vector (15 active / block)
__global__ __launch_bounds__(64) void k_dp(const float* __restrict__ ws, float* __restrict__ T0)
{
    __shared__ float la[1024];
    const int chunk = blockIdx.x;
    const int tid = threadIdx.x;
    const float* A16 = ws + OFF_A + (size_t)chunk * 1024;
    for (int idx = tid; idx < 1024; idx += 64) la[idx] = A16[idx];
    __syncthreads();
    if (tid >= 15) return;
    const int j = tid;
    float s[15];
    #pragma unroll
    for (int i = 0; i < 15; i++) s[i] = (i == j) ? 0.f : NEG;
    #pragma unroll 8
    for (int t = 0; t < 64; t++) {
        float tv[15];
        #pragma unroll
        for (int i = 0; i < 15; i++) tv[i] = s[i] + la[t*16 + i];
        float nw = lse15(tv);
        #pragma unroll
        for (int i = 14; i > 0; i--) s[i] = s[i-1];
        s[0] = nw;
    }
    #pragma unroll
    for (int i = 0; i < 15; i++) T0[chunk*225 + i*15 + j] = s[i];
}

// ---------------------------------------------------------------- tree combine + indiv + out
__global__ __launch_bounds__(1024) void k_final(float* __restrict__ ws,
    const int* __restrict__ tags, const int* __restrict__ lengths,
    float* __restrict__ out)
{
    __shared__ float TA[64*225];
    __shared__ float TB[32*225];
    __shared__ float red[16];
    const int tid = threadIdx.x;
    const float* T0 = ws + OFF_T0;
    float* T1 = ws + OFF_T1;
    // level 0: 256 -> 128 (global -> global)
    for (int e = tid; e < 128*225; e += 1024) {
        int cpair = e / 225, r = e % 225;
        int i = r / 15, jj = r % 15;
        const float* lo = T0 + (2*cpair)*225;
        const float* hi = T0 + (2*cpair + 1)*225;
        float tv[15];
        #pragma unroll
        for (int k = 0; k < 15; k++) tv[k] = hi[i*15+k] + lo[k*15+jj];
        T1[e] = lse15(tv);
    }
    __syncthreads();
    // level 1: 128 -> 64 (global -> LDS)
    for (int e = tid; e < 64*225; e += 1024) {
        int cpair = e / 225, r = e % 225;
        int i = r / 15, jj = r % 15;
        const float* lo = T1 + (2*cpair)*225;
        const float* hi = T1 + (2*cpair + 1)*225;
        float tv[15];
        #pragma unroll
        for (int k = 0; k < 15; k++) tv[k] = hi[i*15+k] + lo[k*15+jj];
        TA[e] = lse15(tv);
    }
    __syncthreads();
    int n = 64;
    float* cur = TA;
    float* oth = TB;
    while (n > 1) {
        int half = n >> 1;
        for (int e = tid; e < half*225; e += 1024) {
            int cpair = e / 225, r = e % 225;
            int i = r / 15, jj = r % 15;
            const float* lo = cur + (2*cpair)*225;
            const float* hi = cur + (2*cpair + 1)*225;
            float tv[15];
            #pragma unroll
            for (int k = 0; k < 15; k++) tv[k] = hi[i*15+k] + lo[k*15+jj];
            oth[e] = lse15(tv);
        }
        __syncthreads();
        float* tsw = cur; cur = oth; oth = tsw;
        n = half;
    }
    const float* gsc = ws + OFF_GSC;
    float loc = 0.f;
    for (int s = tid; s < 2048; s += 1024) {
        int len = lengths[s];
        if (len < 15) loc += gsc[(len-1)*15 + tags[s]];
    }
    #pragma unroll
    for (int off = 32; off > 0; off >>= 1) loc += __shfl_down(loc, off);
    if ((tid & 63) == 0) red[tid >> 6] = loc;
    __syncthreads();
    if (tid == 0) {
        float ind = 0.f;
        #pragma unroll
        for (int w = 0; w < 16; w++) ind += red[w];
        out[0] = cur[0] - ind;
    }
}

// ---------------------------------------------------------------- launcher
extern "C" void kernel_launch(void* const* d_in, const int* in_sizes, int n_in,
                              void* d_out, int out_size, void* d_ws, size_t ws_size,
                              hipStream_t stream)
{
    const float* data = (const float*)d_in[0];
    const float* fWih = (const float*)d_in[1];
    const float* fWhh = (const float*)d_in[2];
    const float* fbih = (const float*)d_in[3];
    const float* fbhh = (const float*)d_in[4];
    const float* bWih = (const float*)d_in[5];
    const float* bWhh = (const float*)d_in[6];
    const float* bbih = (const float*)d_in[7];
    const float* bbhh = (const float*)d_in[8];
    const float* h0f  = (const float*)d_in[9];
    const float* c0f  = (const float*)d_in[10];
    const float* h0b  = (const float*)d_in[11];
    const float* c0b  = (const float*)d_in[12];
    const float* Yenc = (const float*)d_in[13];
    const float* Zenc = (const float*)d_in[14];
    const float* VW   = (const float*)d_in[15];
    const float* Vb   = (const float*)d_in[16];
    const float* WW   = (const float*)d_in[17];
    const float* Wb   = (const float*)d_in[18];
    const int* tags    = (const int*)d_in[19];
    const int* lengths = (const int*)d_in[20];
    float* ws  = (float*)d_ws;
    float* out = (float*)d_out;

    hipLaunchKernelGGL(k_prep, dim3(1), dim3(256), 0, stream,
                       fWih, fWhh, fbih, fbhh, bWih, bWhh, bbih, bbhh,
                       Yenc, Zenc, VW, Vb, ws);
    hipLaunchKernelGGL(k_xg, dim3(256, 2), dim3(512), 0, stream, data, ws, ws);
    hipLaunchKernelGGL(k_lstm, dim3(256, 2), dim3(512), 0, stream,
                       ws, h0f, c0f, h0b, c0b, ws);
    hipLaunchKernelGGL(k_scores, dim3(960), dim3(256), 0, stream,
                       ws, VW, WW, Wb);
    hipLaunchKernelGGL(k_dp, dim3(256), dim3(64), 0, stream, ws, ws + OFF_T0);
    hipLaunchKernelGGL(k_final, dim3(1), dim3(1024), 0, stream,
                       ws, tags, lengths, out);
}

// Round 4
// 259.259 us; speedup vs baseline: 1.2814x; 1.2814x over previous
//
#include <hip/hip_runtime.h>

#define NPOS 16384
#define NEG  (-1e30f)

// workspace offsets (in floats)
#define OFF_WQX_F 0
#define OFF_WQX_B 4096
#define OFF_WQH_F 8192
#define OFF_WQH_B 9216
#define OFF_BQ_F  10240
#define OFF_BQ_B  10304
#define OFF_YP2   10368
#define OFF_ZB    10608
#define OFF_XG_F  16384
#define OFF_XG_B  (OFF_XG_F + 16384*64)
// h states stored as bf16 (ushort); float-offset base, cast to ushort*
#define OFF_FWDH  (OFF_XG_B + 16384*64)
#define OFF_BWDH  (OFF_FWDH + 15*16384*16/2)
#define OFF_A     (OFF_BWDH + 15*16384*16/2)
#define OFF_T0    (OFF_A + 16384*16)
#define OFF_R     (OFF_T0 + 256*225)
#define OFF_GSC   (OFF_R + 16*225)

__device__ __forceinline__ float sigf(float x) {
    return __builtin_amdgcn_rcpf(1.0f + __expf(-x));
}
__device__ __forceinline__ float tanhf_(float x) {
    return 1.0f - 2.0f * __builtin_amdgcn_rcpf(1.0f + __expf(2.0f * x));
}
__device__ __forceinline__ float bf2f(unsigned short u) {
    unsigned int v = ((unsigned int)u) << 16;
    return __builtin_bit_cast(float, v);
}
__device__ __forceinline__ unsigned short f2bf(float f) {
    unsigned int b = __builtin_bit_cast(unsigned int, f);
    return (unsigned short)((b + 0x8000u) >> 16);
}
// tree logsumexp over 15 values (shallow dependent chain)
__device__ __forceinline__ float lse15(const float* tv) {
    float a0 = fmaxf(tv[0], tv[1]),  a1 = fmaxf(tv[2], tv[3]);
    float a2 = fmaxf(tv[4], tv[5]),  a3 = fmaxf(tv[6], tv[7]);
    float a4 = fmaxf(tv[8], tv[9]),  a5 = fmaxf(tv[10], tv[11]);
    float a6 = fmaxf(tv[12], tv[13]);
    float b0 = fmaxf(a0, a1), b1 = fmaxf(a2, a3), b2 = fmaxf(a4, a5), b3 = fmaxf(a6, tv[14]);
    float mx = fmaxf(fmaxf(b0, b1), fmaxf(b2, b3));
    float e[15];
    #pragma unroll
    for (int i = 0; i < 15; i++) e[i] = __expf(tv[i] - mx);
    float s0 = e[0]+e[1], s1 = e[2]+e[3], s2 = e[4]+e[5], s3 = e[6]+e[7];
    float s4 = e[8]+e[9], s5 = e[10]+e[11], s6 = e[12]+e[13];
    float t0 = s0+s1, t1 = s2+s3, t2 = s4+s5, t3 = s6+e[14];
    return mx + __logf((t0+t1) + (t2+t3));
}

// ---------------------------------------------------------------- prep
__global__ void k_prep(const float* __restrict__ fWih, const float* __restrict__ fWhh,
                       const float* __restrict__ fbih, const float* __restrict__ fbhh,
                       const float* __restrict__ bWih, const float* __restrict__ bWhh,
                       const float* __restrict__ bbih, const float* __restrict__ bbhh,
                       const float* __restrict__ Yenc, const float* __restrict__ Zenc,
                       const float* __restrict__ VW,   const float* __restrict__ Vb,
                       float* __restrict__ wp)
{
    int t = threadIdx.x;
    for (int e = t; e < 8192; e += 256) {           // Wih pack: [k][widx]
        int dir = e >> 12, rem = e & 4095;
        int k = rem >> 6, widx = rem & 63;
        int w = widx >> 3, jj = widx & 7;
        int j = (jj >> 1) * 16 + 2 * w + (jj & 1);
        const float* Wih = dir ? bWih : fWih;
        wp[(dir ? OFF_WQX_B : OFF_WQX_F) + rem] = Wih[j * 64 + k];
    }
    for (int e = t; e < 2048; e += 256) {           // Whh pack: [m][widx]
        int dir = e >> 10, rem = e & 1023;
        int m = rem >> 6, widx = rem & 63;
        int w = widx >> 3, jj = widx & 7;
        int j = (jj >> 1) * 16 + 2 * w + (jj & 1);
        const float* Whh = dir ? bWhh : fWhh;
        wp[(dir ? OFF_WQH_B : OFF_WQH_F) + rem] = Whh[j * 16 + m];
    }
    for (int e = t; e < 128; e += 256) {
        int dir = e >> 6, widx = e & 63;
        int w = widx >> 3, jj = widx & 7;
        int j = (jj >> 1) * 16 + 2 * w + (jj & 1);
        const float* bi = dir ? bbih : fbih;
        const float* bh = dir ? bbhh : fbhh;
        wp[(dir ? OFF_BQ_B : OFF_BQ_F) + widx] = bi[j] + bh[j];
    }
    for (int e = t; e < 240; e += 256) {
        int y = e >> 4, h = e & 15;
        float acc = 0.f;                            // yp2 = 2 * (Y_enc @ V2^T)
        for (int tt = 0; tt < 32; tt++) acc += Yenc[y*32+tt] * VW[h*68 + 32 + tt];
        wp[OFF_YP2 + e] = 2.0f * acc;
        float z = Vb[h];                            // zb = Z_enc @ V3^T + V_b
        for (int u = 0; u < 4; u++) z += Zenc[y*4+u] * VW[h*68 + 64 + u];
        wp[OFF_ZB + e] = z;
    }
}

// ---------------------------------------------------------------- xg = x @ Wih^T + b
__global__ __launch_bounds__(512) void k_xg(const float* __restrict__ data,
                                            const float* __restrict__ wp,
                                            float* __restrict__ ws)
{
    const int lane = threadIdx.x & 63;
    const int wv   = __builtin_amdgcn_readfirstlane(threadIdx.x >> 6);
    const int dir  = blockIdx.y;
    const int pos  = (blockIdx.x << 6) + lane;
    const float* WQX = wp + (dir ? OFF_WQX_B : OFF_WQX_F);
    const float* bQ  = wp + (dir ? OFF_BQ_B  : OFF_BQ_F);
    float* xg = ws + (dir ? OFF_XG_B : OFF_XG_F);

    float xv[64];
    const float4* xrow = (const float4*)(data + (size_t)pos * 64);
    #pragma unroll
    for (int q = 0; q < 16; q++) {
        float4 v = xrow[q];
        xv[4*q] = v.x; xv[4*q+1] = v.y; xv[4*q+2] = v.z; xv[4*q+3] = v.w;
    }
    float acc[8];
    #pragma unroll
    for (int jj = 0; jj < 8; jj++) acc[jj] = bQ[wv*8 + jj];
    #pragma unroll 8
    for (int k = 0; k < 64; k++) {
        float xk = xv[k];
        #pragma unroll
        for (int jj = 0; jj < 8; jj++)
            acc[jj] = fmaf(WQX[k*64 + wv*8 + jj], xk, acc[jj]);
    }
    float4* outp = (float4*)(xg + (size_t)pos*64 + wv*8);
    outp[0] = make_float4(acc[0], acc[1], acc[2], acc[3]);
    outp[1] = make_float4(acc[4], acc[5], acc[6], acc[7]);
}

// ---------------------------------------------------------------- LSTM (recurrent part)
__global__ __launch_bounds__(512) void k_lstm(const float* __restrict__ wp,
    const float* __restrict__ h0f, const float* __restrict__ c0f,
    const float* __restrict__ h0b, const float* __restrict__ c0b,
    float* __restrict__ ws)
{
    __shared__ float xgT[64*79];      // [gate j][row r], rows 0..77
    __shared__ float hsh[2][16*64];   // double-buffered h
    const int tid  = threadIdx.x;
    const int lane = tid & 63;
    const int wv   = __builtin_amdgcn_readfirstlane(tid >> 6);
    const int dir  = blockIdx.y;
    const int ms   = wv << 1;
    const int P0   = blockIdx.x << 6;

    const float* xg = ws + (dir ? OFF_XG_B : OFF_XG_F);
    for (int idx = tid; idx < 78*64; idx += 512) {
        int r = idx >> 6, j = idx & 63;
        int q = P0 + r - (dir ? 14 : 0);
        q = q < 0 ? 0 : (q > NPOS-1 ? NPOS-1 : q);
        xgT[j*79 + r] = xg[(size_t)q*64 + j];
    }
    {
        const float* h0 = dir ? h0b : h0f;
        for (int idx = tid; idx < 1024; idx += 512)
            hsh[0][idx] = h0[idx >> 6];
    }
    const float* WQH = wp + (dir ? OFF_WQH_B : OFF_WQH_F);
    const float* c0 = dir ? c0b : c0f;
    unsigned int* outH = (unsigned int*)(ws + (dir ? OFF_BWDH : OFF_FWDH));
    float c0v = c0[ms], c1v = c0[ms + 1];
    __syncthreads();

    int buf = 0;
    for (int d = 0; d < 15; d++) {
        const int row = dir ? (lane + 14 - d) : (lane + d);
        float part[8];
        #pragma unroll
        for (int jj = 0; jj < 8; jj++) part[jj] = xgT[(wv*8 + jj)*79 + row];
        #pragma unroll
        for (int m = 0; m < 16; m++) {
            float hm = hsh[buf][m*64 + lane];
            #pragma unroll
            for (int jj = 0; jj < 8; jj++)
                part[jj] = fmaf(WQH[m*64 + wv*8 + jj], hm, part[jj]);
        }
        float cn0 = sigf(part[2])*c0v + sigf(part[0])*tanhf_(part[4]);
        float cn1 = sigf(part[3])*c1v + sigf(part[1])*tanhf_(part[5]);
        c0v = cn0; c1v = cn1;
        float h0v = sigf(part[6])*tanhf_(cn0);
        float h1v = sigf(part[7])*tanhf_(cn1);
        hsh[buf^1][ms*64 + lane]     = h0v;
        hsh[buf^1][(ms+1)*64 + lane] = h1v;
        unsigned int pk = (unsigned int)f2bf(h0v) | ((unsigned int)f2bf(h1v) << 16);
        outH[((size_t)d*NPOS + P0 + lane)*8 + wv] = pk;
        __syncthreads();
        buf ^= 1;
    }
}

// ---------------------------------------------------------------- scores + A
__global__ __launch_bounds__(256) void k_scores(float* __restrict__ ws,
    const float* __restrict__ VW, const float* __restrict__ WW,
    const float* __restrict__ Wb)
{
    const int g = blockIdx.x * 256 + threadIdx.x;
    const int p = g & (NPOS - 1);
    const int d = __builtin_amdgcn_readfirstlane(g >> 14);
    float* A16 = ws + OFF_A;
    if (d == 0) A16[p*16 + 15] = NEG;   // pad column
    if (p < d) { A16[p*16 + d] = NEG; return; }

    const uint4* fptr = (const uint4*)((const unsigned short*)(ws + OFF_FWDH)
                        + ((size_t)d*NPOS + (p - d))*16);
    const uint4* bptr = (const uint4*)((const unsigned short*)(ws + OFF_BWDH)
                        + ((size_t)d*NPOS + p)*16);
    float fb0[16], fb1[16];
    #pragma unroll
    for (int q = 0; q < 2; q++) {
        uint4 v = fptr[q];
        unsigned int ww[4] = {v.x, v.y, v.z, v.w};
        #pragma unroll
        for (int t = 0; t < 4; t++) {
            fb0[q*8 + 2*t]     = bf2f((unsigned short)(ww[t] & 0xffff));
            fb0[q*8 + 2*t + 1] = bf2f((unsigned short)(ww[t] >> 16));
        }
        uint4 u = bptr[q];
        unsigned int uu[4] = {u.x, u.y, u.z, u.w};
        #pragma unroll
        for (int t = 0; t < 4; t++) {
            fb1[q*8 + 2*t]     = bf2f((unsigned short)(uu[t] & 0xffff));
            fb1[q*8 + 2*t + 1] = bf2f((unsigned short)(uu[t] >> 16));
        }
    }
    const float* zb  = ws + OFF_ZB + d*16;
    const float* yp2 = ws + OFF_YP2;
    float base2[16], w2[16], wsum = 0.f;
    #pragma unroll
    for (int h = 0; h < 16; h++) {
        float acc = zb[h];
        #pragma unroll
        for (int m = 0; m < 16; m++) acc = fmaf(VW[h*68 + m],      fb0[m], acc);
        #pragma unroll
        for (int m = 0; m < 16; m++) acc = fmaf(VW[h*68 + 16 + m], fb1[m], acc);
        base2[h] = acc + acc;
        float w = WW[h];
        w2[h] = -2.0f * w;
        wsum += w;
    }
    const float cst = Wb[0] + wsum;
    float sc[15];
    #pragma unroll
    for (int y = 0; y < 15; y++) {
        float a = 0.f;
        #pragma unroll
        for (int h = 0; h < 16; h++) {
            float t = __expf(base2[h] + yp2[y*16 + h]);
            a = fmaf(w2[h], __builtin_amdgcn_rcpf(1.0f + t), a);
        }
        sc[y] = cst + a;
    }
    A16[p*16 + d] = lse15(sc);
    if (p == d && p < 15) {
        float* gsc = ws + OFF_GSC;
        #pragma unroll
        for (int y = 0; y < 15; y++) gsc[p*15 + y] = sc[y];
    }
}

// ---------------------------------------------------------------- DP chunk transfer matrices
// 256 chunks of 64 steps; thread = basis vector (15 active / block)
__global__ __launch_bounds__(64) void k_dp(const float* __restrict__ ws, float* __restrict__ T0)
{
    __shared__ float la[1024];
    const int chunk = blockIdx.x;
    const int tid = threadIdx.x;
    const float* A16 = ws + OFF_A + (size_t)chunk * 1024;
    for (int idx = tid; idx < 1024; idx += 64) la[idx] = A16[idx];
    __syncthreads();
    if (tid >= 15) return;
    const int j = tid;
    float s[15];
    #pragma unroll
    for (int i = 0; i < 15; i++) s[i] = (i == j) ? 0.f : NEG;
    #pragma unroll 8
    for (int t = 0; t < 64; t++) {
        float tv[15];
        #pragma unroll
        for (int i = 0; i < 15; i++) tv[i] = s[i] + la[t*16 + i];
        float nw = lse15(tv);
        #pragma unroll
        for (int i = 14; i > 0; i--) s[i] = s[i-1];
        s[0] = nw;
    }
    #pragma unroll
    for (int i = 0; i < 15; i++) T0[chunk*225 + i*15 + j] = s[i];
}

// ---------------------------------------------------------------- combine 16 chunks per block
// 16 blocks x 256 thr. Block b: R = T_{16b+15} (*) ... (*) T_{16b}. R in LDS.
__global__ __launch_bounds__(256) void k_comb(const float* __restrict__ T0,
                                              float* __restrict__ Rg)
{
    __shared__ float Rm[240];         // [k][j] stride 16
    const int tid = threadIdx.x;
    const int e = tid;                // 0..224 active
    const int i = e / 15, j = e % 15;
    const int c0 = blockIdx.x * 16;
    if (e < 225) Rm[i*16 + j] = T0[c0*225 + e];
    __syncthreads();
    for (int t = 1; t < 16; t++) {
        float nw = 0.f;
        if (e < 225) {
            const float* Trow = T0 + (c0 + t)*225 + i*15;
            float tv[15];
            #pragma unroll
            for (int k = 0; k < 15; k++) tv[k] = Trow[k] + Rm[k*16 + j];
            nw = lse15(tv);
        }
        __syncthreads();
        if (e < 225) Rm[i*16 + j] = nw;
        __syncthreads();
    }
    if (e < 225) Rg[blockIdx.x*225 + e] = Rm[i*16 + j];
}

// ---------------------------------------------------------------- final combine + indiv + out
__global__ __launch_bounds__(256) void k_final(const float* __restrict__ ws,
    const int* __restrict__ tags, const int* __restrict__ lengths,
    float* __restrict__ out)
{
    __shared__ float RA[16*240];      // 16 matrices, [t][i*16+j]
    __shared__ float G[240];
    __shared__ float red[4];
    const int tid = threadIdx.x;
    const float* Rg = ws + OFF_R;
    for (int idx = tid; idx < 16*225; idx += 256) {
        int t = idx / 225, r = idx % 225;
        RA[t*240 + (r/15)*16 + (r%15)] = Rg[idx];
    }
    __syncthreads();
    const int e = tid, i = e / 15, j = e % 15;
    if (e < 225) G[i*16 + j] = RA[i*16 + j];
    __syncthreads();
    for (int t = 1; t < 16; t++) {
        float nw = 0.f;
        if (e < 225) {
            float tv[15];
            #pragma unroll
            for (int k = 0; k < 15; k++) tv[k] = RA[t*240 + i*16 + k] + G[k*16 + j];
            nw = lse15(tv);
        }
        __syncthreads();
        if (e < 225) G[i*16 + j] = nw;
        __syncthreads();
    }
    // indiv
    const float* gsc = ws + OFF_GSC;
    float loc = 0.f;
    for (int s = tid; s < 2048; s += 256) {
        int len = lengths[s];
        if (len < 15) loc += gsc[(len-1)*15 + tags[s]];
    }
    #pragma unroll
    for (int off = 32; off > 0; off >>= 1) loc += __shfl_down(loc, off);
    if ((tid & 63) == 0) red[tid >> 6] = loc;
    __syncthreads();
    if (tid == 0) {
        float ind = red[0] + red[1] + red[2] + red[3];
        out[0] = G[0] - ind;
    }
}

// ---------------------------------------------------------------- launcher
extern "C" void kernel_launch(void* const* d_in, const int* in_sizes, int n_in,
                              void* d_out, int out_size, void* d_ws, size_t ws_size,
                              hipStream_t stream)
{
    const float* data = (const float*)d_in[0];
    const float* fWih = (const float*)d_in[1];
    const float* fWhh = (const float*)d_in[2];
    const float* fbih = (const float*)d_in[3];
    const float* fbhh = (const float*)d_in[4];
    const float* bWih = (const float*)d_in[5];
    const float* bWhh = (const float*)d_in[6];
    const float* bbih = (const float*)d_in[7];
    const float* bbhh = (const float*)d_in[8];
    const float* h0f  = (const float*)d_in[9];
    const float* c0f  = (const float*)d_in[10];
    const float* h0b  = (const float*)d_in[11];
    const float* c0b  = (const float*)d_in[12];
    const float* Yenc = (const float*)d_in[13];
    const float* Zenc = (const float*)d_in[14];
    const float* VW   = (const float*)d_in[15];
    const float* Vb   = (const float*)d_in[16];
    const float* WW   = (const float*)d_in[17];
    const float* Wb   = (const float*)d_in[18];
    const int* tags    = (const int*)d_in[19];
    const int* lengths = (const int*)d_in[20];
    float* ws  = (float*)d_ws;
    float* out = (float*)d_out;

    hipLaunchKernelGGL(k_prep, dim3(1), dim3(256), 0, stream,
                       fWih, fWhh, fbih, fbhh, bWih, bWhh, bbih, bbhh,
                       Yenc, Zenc, VW, Vb, ws);
    hipLaunchKernelGGL(k_xg, dim3(256, 2), dim3(512), 0, stream, data, ws, ws);
    hipLaunchKernelGGL(k_lstm, dim3(256, 2), dim3(512), 0, stream,
                       ws, h0f, c0f, h0b, c0b, ws);
    hipLaunchKernelGGL(k_scores, dim3(960), dim3(256), 0, stream,
                       ws, VW, WW, Wb);
    hipLaunchKernelGGL(k_dp, dim3(256), dim3(64), 0, stream, ws, ws + OFF_T0);
    hipLaunchKernelGGL(k_comb, dim3(16), dim3(256), 0, stream, ws + OFF_T0, ws + OFF_R);
    hipLaunchKernelGGL(k_final, dim3(1), dim3(256), 0, stream,
                       ws, tags, lengths, out);
}